// Round 5
// baseline (224.221 us; speedup 1.0000x reference)
//
#include <hip/hip_runtime.h>
#include <hip/hip_bf16.h>
#include <math.h>

#define NB  32
#define NT  200
#define NTQ 50
#define NE  64
#define NP  128
#define NC  64
#define NU  36
#define NROW (NB * NTQ)   // 1600

typedef __attribute__((ext_vector_type(8))) short bf8;   // 8 bf16 in 4 VGPRs
typedef __attribute__((ext_vector_type(4))) float f4;

// ---- ws layout (bf16 elements from base of d_ws) ----
//   wm1f: [16*8][64][8]   @ 0       (65536)
//   wm2f: [8*8][64][8]    @ 65536   (32768)
//   wm3f: [4*4][64][8]    @ 98304   (8192)
//   Hh  : [1600][64]      @ 106496  (102400)  attn interest (bn1'd), bf16
#define WM1F_OFF 0
#define WM2F_OFF 65536
#define WM3F_OFF 98304
#define HH_OFF   106496

#define ATTN_BLOCKS 1600
#define PACK_ELEMS  (65536 + 32768 + 8192)          // 106496
#define PACK_BLOCKS ((PACK_ELEMS + 255) / 256)      // 416

__device__ __forceinline__ short f2bf(float x) {
    __hip_bfloat16 h = __float2bfloat16(x);
    return __builtin_bit_cast(short, h);
}

// pack one element of a trunk weight fragment buffer
__device__ __forceinline__ void pack_frag(int j, const float* W, int N, int ksc, short* dst) {
    int i    = j & 7;
    int lane = (j >> 3) & 63;
    int tile = j >> 9;
    int ks = tile % ksc;
    int nt = tile / ksc;
    int k = ks * 32 + 8 * (lane >> 4) + i;
    int n = nt * 16 + (lane & 15);
    dst[j] = f2bf(W[k * N + n]);
}

// ---------------------------------------------------------------------------
// Kernel 1: blocks [0,1600): attention per (b,tq) with K=192 MFMA
//           ( [q | q*k | k] @ [(W1a+W1c) | W1d | (W1b-W1c)] ), dice + W2,
//           interest reduction, BN1 -> Hh (1600 x 64 bf16).
//           blocks [1600,2016): pack trunk weight fragments.
// ---------------------------------------------------------------------------
struct AParams {
    const float *ub, *it, *W1, *b1, *W2, *b2, *da, *dm, *dv;
    const float *bn1_g, *bn1_b, *bn1_m, *bn1_v;
    const float *Wm1, *Wm2, *Wm3;
    short *wm1f, *wm2f, *wm3f;
    short* Hh;
};

__global__ __launch_bounds__(256) void attn(AParams P) {
    const int bid = blockIdx.x;
    const int tid = threadIdx.x;

    if (bid >= ATTN_BLOCKS) {                 // ---- pack path ----
        int j = (bid - ATTN_BLOCKS) * 256 + tid;
        if (j < 65536) { pack_frag(j, P.Wm1, 256, 8, P.wm1f); return; }
        j -= 65536;
        if (j < 32768) { pack_frag(j, P.Wm2, 128, 8, P.wm2f); return; }
        j -= 32768;
        if (j < 8192)  { pack_frag(j, P.Wm3,  64, 4, P.wm3f); }
        return;
    }

    __shared__ float w_s[NT];
    __shared__ float red_s[256];

    const int l = tid & 63, w = tid >> 6;
    const int tq = bid % NTQ, b = bid / NTQ;

    // ---- self-pack B-fragments from W1 (L1-resident, once per block) ----
    // B rows kk: [0,64): W1a+W1c ; [64,128): W1d ; [128,192): W1b-W1c
    const int ul = l & 15;
    bf8 bfr[3][6];
    #pragma unroll
    for (int nt = 0; nt < 3; ++nt) {
        int n = nt * 16 + ul;
        bool nv = (n < NU);
        #pragma unroll
        for (int ks = 0; ks < 6; ++ks) {
            #pragma unroll
            for (int i = 0; i < 8; ++i) {
                int kk = ks * 32 + 8 * (l >> 4) + i;
                float v = 0.f;
                if (nv) {
                    if (kk < 128) {
                        v = P.W1[(128 + kk) * NU + n];
                        if (kk < 64) v += P.W1[kk * NU + n];
                    } else {
                        v = P.W1[(kk - 64) * NU + n] - P.W1[kk * NU + n];
                    }
                }
                bfr[nt][ks][i] = f2bf(v);
            }
        }
    }

    // this lane's it[e] values at A-frag k positions: e = ks*32 + 8*(l>>4) + i
    float itv[2][8];
    bf8 ak[2];
    {
        const float* itr = P.it + ((size_t)b * NTQ + tq) * NE;
        #pragma unroll
        for (int ks = 0; ks < 2; ++ks) {
            int e0 = ks * 32 + 8 * (l >> 4);
            f4 v0 = *(const f4*)(itr + e0);
            f4 v1 = *(const f4*)(itr + e0 + 4);
            #pragma unroll
            for (int i = 0; i < 4; ++i) {
                itv[ks][i] = v0[i]; itv[ks][4 + i] = v1[i];
                ak[ks][i] = f2bf(v0[i]); ak[ks][4 + i] = f2bf(v1[i]);
            }
        }
    }

    // base accumulator: k @ (W1b - W1c)  (rows identical across t)
    f4 acc0[3];
    #pragma unroll
    for (int nt = 0; nt < 3; ++nt) {
        f4 z; z[0]=0.f; z[1]=0.f; z[2]=0.f; z[3]=0.f;
        z = __builtin_amdgcn_mfma_f32_16x16x32_bf16(ak[0], bfr[nt][4], z, 0, 0, 0);
        z = __builtin_amdgcn_mfma_f32_16x16x32_bf16(ak[1], bfr[nt][5], z, 0, 0, 0);
        acc0[nt] = z;
    }

    // per-u (output column) constants
    float b1v[3], dmv[3], drs[3], dav[3], w2v[3];
    #pragma unroll
    for (int nt = 0; nt < 3; ++nt) {
        int u = nt * 16 + ul;
        bool v = (u < NU);
        int uc = v ? u : (NU - 1);
        b1v[nt] = P.b1[uc];
        dmv[nt] = P.dm[uc];
        drs[nt] = rsqrtf(P.dv[uc] + 1e-6f);
        dav[nt] = P.da[uc];
        w2v[nt] = v ? P.W2[uc] : 0.f;
    }
    const float b2s = P.b2[0];

    for (int tt = w; tt < 13; tt += 4) {
        const int t0 = tt * 16;
        const int tA = t0 + (l & 15);           // A-frag row

        bf8 aq[2], ap[2];
        if (tA < NT) {
            const float* ubr = P.ub + ((size_t)b * NT + tA) * NE;
            #pragma unroll
            for (int ks = 0; ks < 2; ++ks) {
                int e0 = ks * 32 + 8 * (l >> 4);
                f4 u0 = *(const f4*)(ubr + e0);
                f4 u1 = *(const f4*)(ubr + e0 + 4);
                #pragma unroll
                for (int i = 0; i < 4; ++i) {
                    aq[ks][i]     = f2bf(u0[i]);
                    aq[ks][4 + i] = f2bf(u1[i]);
                    ap[ks][i]     = f2bf(u0[i] * itv[ks][i]);
                    ap[ks][4 + i] = f2bf(u1[i] * itv[ks][4 + i]);
                }
            }
        } else {
            #pragma unroll
            for (int ks = 0; ks < 2; ++ks)
                #pragma unroll
                for (int i = 0; i < 8; ++i) { aq[ks][i] = 0; ap[ks][i] = 0; }
        }

        f4 acc[3];
        #pragma unroll
        for (int nt = 0; nt < 3; ++nt) acc[nt] = acc0[nt];
        #pragma unroll
        for (int nt = 0; nt < 3; ++nt) {
            acc[nt] = __builtin_amdgcn_mfma_f32_16x16x32_bf16(aq[0], bfr[nt][0], acc[nt], 0, 0, 0);
            acc[nt] = __builtin_amdgcn_mfma_f32_16x16x32_bf16(aq[1], bfr[nt][1], acc[nt], 0, 0, 0);
            acc[nt] = __builtin_amdgcn_mfma_f32_16x16x32_bf16(ap[0], bfr[nt][2], acc[nt], 0, 0, 0);
            acc[nt] = __builtin_amdgcn_mfma_f32_16x16x32_bf16(ap[1], bfr[nt][3], acc[nt], 0, 0, 0);
        }

        // epilogue: D row = t0 + 4*(l>>4) + i, col u = nt*16 + (l&15)
        const int tD = t0 + 4 * (l >> 4);
        #pragma unroll
        for (int i = 0; i < 4; ++i) {
            int t = tD + i;
            bool tv = (t < NT);
            float val = 0.f;
            #pragma unroll
            for (int nt = 0; nt < 3; ++nt) {
                float x = acc[nt][i] + b1v[nt];
                float z = (x - dmv[nt]) * drs[nt];
                float p = 1.f / (1.f + __expf(-z));
                val += x * (dav[nt] + p * (1.f - dav[nt])) * w2v[nt];
            }
            val += __shfl_xor(val, 1);
            val += __shfl_xor(val, 2);
            val += __shfl_xor(val, 4);
            val += __shfl_xor(val, 8);
            if (ul == 0 && tv) w_s[t] = val + b2s;
        }
    }
    __syncthreads();

    // interest[e] = sum_t w[t]*ub[b,t,e]; BN1; write bf16 Hh row (64 wide)
    {
        const int e = tid & 63, g = tid >> 6;
        const float* ubb = P.ub + (size_t)b * NT * NE;
        float s = 0.f;
        #pragma unroll 5
        for (int t = g * 50; t < g * 50 + 50; ++t)
            s = fmaf(w_s[t], ubb[t * NE + e], s);
        red_s[tid] = s;
    }
    __syncthreads();
    if (tid < 64) {
        float tot = red_s[tid] + red_s[64 + tid] + red_s[128 + tid] + red_s[192 + tid];
        float hn = (tot - P.bn1_m[tid]) * rsqrtf(P.bn1_v[tid] + 1e-6f) * P.bn1_g[tid] + P.bn1_b[tid];
        P.Hh[((size_t)b * NTQ + tq) * 64 + tid] = f2bf(hn);
    }
}

// ---------------------------------------------------------------------------
// Kernel 2: batched trunk MLP. 100 blocks x 16 rows; 4 waves, wave w owns
// an N-quarter. Staging computes bn1(profile||context) cols on the fly.
// ---------------------------------------------------------------------------
struct TParams {
    const short *Hh, *wm1f, *wm2f, *wm3f;
    const float *up, *cx;
    const float *bn1_g, *bn1_b, *bn1_m, *bn1_v;
    const float *bm1, *bm2, *bm3;
    const float *bn2_g, *bn2_b, *bn2_m, *bn2_v;
    const float *bn3_g, *bn3_b, *bn3_m, *bn3_v;
    float* out;
};

#define LSTR 264   // bf16 row stride: 528B -> <=2-way bank aliasing (free)

__global__ __launch_bounds__(256) void trunk(TParams P) {
    __shared__ short Ha[16 * LSTR];
    __shared__ short Hb[16 * LSTR];

    const int tid = threadIdx.x;
    const int l = tid & 63, w = tid >> 6;
    const int row0 = blockIdx.x * 16;

    // stage cols 0..63 from Hh (attn output, already bn1'd)
    {
        const bf8* src = (const bf8*)(P.Hh + (size_t)row0 * 64);
        for (int ch = tid; ch < 16 * 8; ch += 256) {
            int r = ch >> 3, c8 = ch & 7;
            *(bf8*)&Ha[r * LSTR + c8 * 8] = src[r * 8 + c8];
        }
    }
    // stage cols 64..255 = bn1(profile || context), computed on the fly
    for (int ch = tid; ch < 16 * 192; ch += 256) {
        int r = ch / 192, c = ch % 192;
        int col = 64 + c;
        int b = (row0 + r) / NTQ;
        float val = (c < NP) ? P.up[b * NP + c] : P.cx[b * NC + (c - NP)];
        float hn = (val - P.bn1_m[col]) * rsqrtf(P.bn1_v[col] + 1e-6f)
                   * P.bn1_g[col] + P.bn1_b[col];
        Ha[r * LSTR + col] = f2bf(hn);
    }
    __syncthreads();

    const int ar = l & 15;            // A-frag row
    const int rl = 4 * (l >> 4);      // D row base
    const int nl = l & 15;            // D col within n-tile

    // ---- layer 1: K=256, N=256 : Ha -> Hb, relu then BN2 ----
    {
        bf8 a[8];
        #pragma unroll
        for (int ks = 0; ks < 8; ++ks)
            a[ks] = *(const bf8*)&Ha[ar * LSTR + ks * 32 + 8 * (l >> 4)];
        const bf8* wf = (const bf8*)P.wm1f;
        #pragma unroll
        for (int nt0 = 0; nt0 < 4; ++nt0) {
            int nt = w * 4 + nt0;
            f4 acc; acc[0]=0.f; acc[1]=0.f; acc[2]=0.f; acc[3]=0.f;
            #pragma unroll
            for (int ks = 0; ks < 8; ++ks)
                acc = __builtin_amdgcn_mfma_f32_16x16x32_bf16(a[ks], wf[(nt * 8 + ks) * 64 + l], acc, 0, 0, 0);
            int n = nt * 16 + nl;
            float g1 = P.bn2_g[n] * rsqrtf(P.bn2_v[n] + 1e-6f);
            float c1 = P.bn2_b[n] - P.bn2_m[n] * g1;
            float bias = P.bm1[n];
            #pragma unroll
            for (int i = 0; i < 4; ++i) {
                float v = fmaxf(acc[i] + bias, 0.f);
                Hb[(rl + i) * LSTR + n] = f2bf(v * g1 + c1);
            }
        }
    }
    __syncthreads();

    // ---- layer 2: K=256, N=128 : Hb -> Ha[:,0:128], relu then BN3 ----
    {
        bf8 a[8];
        #pragma unroll
        for (int ks = 0; ks < 8; ++ks)
            a[ks] = *(const bf8*)&Hb[ar * LSTR + ks * 32 + 8 * (l >> 4)];
        const bf8* wf = (const bf8*)P.wm2f;
        #pragma unroll
        for (int nt0 = 0; nt0 < 2; ++nt0) {
            int nt = w * 2 + nt0;
            f4 acc; acc[0]=0.f; acc[1]=0.f; acc[2]=0.f; acc[3]=0.f;
            #pragma unroll
            for (int ks = 0; ks < 8; ++ks)
                acc = __builtin_amdgcn_mfma_f32_16x16x32_bf16(a[ks], wf[(nt * 8 + ks) * 64 + l], acc, 0, 0, 0);
            int n = nt * 16 + nl;
            float g1 = P.bn3_g[n] * rsqrtf(P.bn3_v[n] + 1e-6f);
            float c1 = P.bn3_b[n] - P.bn3_m[n] * g1;
            float bias = P.bm2[n];
            #pragma unroll
            for (int i = 0; i < 4; ++i) {
                float v = fmaxf(acc[i] + bias, 0.f);
                Ha[(rl + i) * LSTR + n] = f2bf(v * g1 + c1);
            }
        }
    }
    __syncthreads();

    // ---- layer 3: K=128, N=64 : Ha[:,0:128] -> out, relu ----
    {
        bf8 a[4];
        #pragma unroll
        for (int ks = 0; ks < 4; ++ks)
            a[ks] = *(const bf8*)&Ha[ar * LSTR + ks * 32 + 8 * (l >> 4)];
        const bf8* wf = (const bf8*)P.wm3f;
        {
            int nt = w;
            f4 acc; acc[0]=0.f; acc[1]=0.f; acc[2]=0.f; acc[3]=0.f;
            #pragma unroll
            for (int ks = 0; ks < 4; ++ks)
                acc = __builtin_amdgcn_mfma_f32_16x16x32_bf16(a[ks], wf[(nt * 4 + ks) * 64 + l], acc, 0, 0, 0);
            int n = nt * 16 + nl;
            float bias = P.bm3[n];
            #pragma unroll
            for (int i = 0; i < 4; ++i)
                P.out[(size_t)(row0 + rl + i) * 64 + n] = fmaxf(acc[i] + bias, 0.f);
        }
    }
}

// ---------------------------------------------------------------------------
extern "C" void kernel_launch(void* const* d_in, const int* in_sizes, int n_in,
                              void* d_out, int out_size, void* d_ws, size_t ws_size,
                              hipStream_t stream) {
    (void)in_sizes; (void)n_in; (void)out_size; (void)ws_size;

    const float* ub         = (const float*)d_in[0];
    const float* it         = (const float*)d_in[1];
    const float* up         = (const float*)d_in[2];
    const float* cx         = (const float*)d_in[3];
    const float* W1         = (const float*)d_in[4];
    const float* b1         = (const float*)d_in[5];
    const float* dice_alpha = (const float*)d_in[6];
    const float* dice_mean  = (const float*)d_in[7];
    const float* dice_var   = (const float*)d_in[8];
    const float* W2         = (const float*)d_in[9];
    const float* b2         = (const float*)d_in[10];
    const float* bn1_g      = (const float*)d_in[11];
    const float* bn1_b      = (const float*)d_in[12];
    const float* bn1_m      = (const float*)d_in[13];
    const float* bn1_v      = (const float*)d_in[14];
    const float* Wm1        = (const float*)d_in[15];
    const float* bm1        = (const float*)d_in[16];
    const float* bn2_g      = (const float*)d_in[17];
    const float* bn2_b      = (const float*)d_in[18];
    const float* bn2_m      = (const float*)d_in[19];
    const float* bn2_v      = (const float*)d_in[20];
    const float* Wm2        = (const float*)d_in[21];
    const float* bm2        = (const float*)d_in[22];
    const float* bn3_g      = (const float*)d_in[23];
    const float* bn3_b      = (const float*)d_in[24];
    const float* bn3_m      = (const float*)d_in[25];
    const float* bn3_v      = (const float*)d_in[26];
    const float* Wm3        = (const float*)d_in[27];
    const float* bm3        = (const float*)d_in[28];

    short* wsb  = (short*)d_ws;
    short* wm1f = wsb + WM1F_OFF;
    short* wm2f = wsb + WM2F_OFF;
    short* wm3f = wsb + WM3F_OFF;
    short* Hh   = wsb + HH_OFF;

    AParams A;
    A.ub = ub; A.it = it; A.W1 = W1; A.b1 = b1;
    A.W2 = W2; A.b2 = b2; A.da = dice_alpha; A.dm = dice_mean; A.dv = dice_var;
    A.bn1_g = bn1_g; A.bn1_b = bn1_b; A.bn1_m = bn1_m; A.bn1_v = bn1_v;
    A.Wm1 = Wm1; A.Wm2 = Wm2; A.Wm3 = Wm3;
    A.wm1f = wm1f; A.wm2f = wm2f; A.wm3f = wm3f;
    A.Hh = Hh;
    attn<<<ATTN_BLOCKS + PACK_BLOCKS, 256, 0, stream>>>(A);

    TParams T;
    T.Hh = Hh; T.wm1f = wm1f; T.wm2f = wm2f; T.wm3f = wm3f;
    T.up = up; T.cx = cx;
    T.bn1_g = bn1_g; T.bn1_b = bn1_b; T.bn1_m = bn1_m; T.bn1_v = bn1_v;
    T.bm1 = bm1; T.bm2 = bm2; T.bm3 = bm3;
    T.bn2_g = bn2_g; T.bn2_b = bn2_b; T.bn2_m = bn2_m; T.bn2_v = bn2_v;
    T.bn3_g = bn3_g; T.bn3_b = bn3_b; T.bn3_m = bn3_m; T.bn3_v = bn3_v;
    T.out = (float*)d_out;
    trunk<<<NROW / 16, 256, 0, stream>>>(T);
}

// Round 6
// 149.397 us; speedup vs baseline: 1.5008x; 1.5008x over previous
//
#include <hip/hip_runtime.h>
#include <hip/hip_bf16.h>
#include <math.h>

#define NB  32
#define NT  200
#define NTQ 50
#define NE  64
#define NP  128
#define NC  64
#define NU  36
#define NROW (NB * NTQ)   // 1600

typedef __attribute__((ext_vector_type(8))) short bf8;   // 8 bf16 in 4 VGPRs
typedef __attribute__((ext_vector_type(4))) float f4;

// ---- ws layout (bf16 elements from base of d_ws) ----
//   wm1f: [16*8][64][8]   @ 0       (65536)
//   wm2f: [8*8][64][8]    @ 65536   (32768)
//   wm3f: [4*4][64][8]    @ 98304   (8192)
//   w1f : [3][6][64][8]   @ 106496  (9216)   attn B frags (q|qk|k blocks)
//   Hh  : [1600][64]      @ 115712  (102400) attn interest (bn1'd), bf16
#define WM1F_OFF 0
#define WM2F_OFF 65536
#define WM3F_OFF 98304
#define W1F_OFF  106496
#define HH_OFF   115712

#define ATTN_BLOCKS 1600
#define PACK_ELEMS  (65536 + 32768 + 8192)          // 106496
#define PACK_BLOCKS (PACK_ELEMS / 256)              // 416

__device__ __forceinline__ short f2bf(float x) {
    __hip_bfloat16 h = __float2bfloat16(x);
    return __builtin_bit_cast(short, h);
}
__device__ __forceinline__ float bf2f(short s) {
    unsigned u = ((unsigned)(unsigned short)s) << 16;
    return __builtin_bit_cast(float, u);
}

// ---------------------------------------------------------------------------
// Kernel 0 (tiny): pack w1f = [ (W1a+W1c) | W1d | (W1b-W1c) ] fragments.
// 9216 elements = 36 blocks. Runs before attn (attn consumes w1f).
// ---------------------------------------------------------------------------
__global__ __launch_bounds__(256) void prep_w1(const float* __restrict__ W1,
                                               short* __restrict__ w1f) {
    int j = blockIdx.x * 256 + threadIdx.x;   // < 9216 exactly
    int i = j & 7, lane = (j >> 3) & 63, tile = j >> 9;  // tile = nt*6+ks
    int ks = tile % 6, nt = tile / 6;
    int kk = ks * 32 + 8 * (lane >> 4) + i;   // 0..191
    int n  = nt * 16 + (lane & 15);           // u in 0..47 (pad >=36 with 0)
    float v = 0.f;
    if (n < NU) {
        if (kk < 128) {                       // q-block (+W1a) and qk-block
            v = W1[(128 + kk) * NU + n];
            if (kk < 64) v += W1[kk * NU + n];
        } else {                              // k-block: W1b - W1c
            v = W1[(kk - 64) * NU + n] - W1[kk * NU + n];
        }
    }
    w1f[j] = f2bf(v);
}

// ---------------------------------------------------------------------------
// Kernel 1: blocks [0,1600): attention per (b,tq).
//   K=192 MFMA: [q | q*k | k] @ w1f; k-block folded into a per-wave base
//   accumulator (6 MFMAs once, k-frags transient). Dice + W2 epilogue,
//   interest reduction, BN1 -> Hh (1600 x 64 bf16).
// blocks [1600,2016): pack trunk weight fragments (consumed by kernel 2).
// ---------------------------------------------------------------------------
__device__ __forceinline__ void pack_frag(int j, const float* W, int N, int ksc, short* dst) {
    int i    = j & 7;
    int lane = (j >> 3) & 63;
    int tile = j >> 9;
    int ks = tile % ksc;
    int nt = tile / ksc;
    int k = ks * 32 + 8 * (lane >> 4) + i;
    int n = nt * 16 + (lane & 15);
    dst[j] = f2bf(W[k * N + n]);
}

struct AParams {
    const float *ub, *it, *b1, *W2, *b2, *da, *dm, *dv;
    const float *bn1_g, *bn1_b, *bn1_m, *bn1_v;
    const float *Wm1, *Wm2, *Wm3;
    const short *w1f;
    short *wm1f, *wm2f, *wm3f;
    short* Hh;
};

__global__ __launch_bounds__(256) void attn(AParams P) {
    const int bid = blockIdx.x;
    const int tid = threadIdx.x;

    if (bid >= ATTN_BLOCKS) {                 // ---- pack path ----
        int j = (bid - ATTN_BLOCKS) * 256 + tid;
        if (j < 65536) { pack_frag(j, P.Wm1, 256, 8, P.wm1f); return; }
        j -= 65536;
        if (j < 32768) { pack_frag(j, P.Wm2, 128, 8, P.wm2f); return; }
        j -= 32768;
        pack_frag(j, P.Wm3, 64, 4, P.wm3f);
        return;
    }

    __shared__ float w_s[NT];
    __shared__ float red_s[256];

    const int l = tid & 63, w = tid >> 6;
    const int tq = bid % NTQ, b = bid / NTQ;
    const int ul = l & 15;

    const bf8* wf = (const bf8*)P.w1f;

    // persistent B-fragments: q-block + qk-block (12 x bf8 = 48 VGPR)
    bf8 bfr[3][4];
    #pragma unroll
    for (int nt = 0; nt < 3; ++nt)
        #pragma unroll
        for (int ks = 0; ks < 4; ++ks)
            bfr[nt][ks] = wf[(nt * 6 + ks) * 64 + l];

    // k (item) vector as bf16 at A-frag k positions: e = ks*32 + 8*(l>>4) + i
    bf8 ak[2];
    {
        const float* itr = P.it + ((size_t)b * NTQ + tq) * NE;
        #pragma unroll
        for (int ks = 0; ks < 2; ++ks) {
            int e0 = ks * 32 + 8 * (l >> 4);
            f4 v0 = *(const f4*)(itr + e0);
            f4 v1 = *(const f4*)(itr + e0 + 4);
            #pragma unroll
            for (int i = 0; i < 4; ++i) {
                ak[ks][i]     = f2bf(v0[i]);
                ak[ks][4 + i] = f2bf(v1[i]);
            }
        }
    }

    // base accumulator: k @ (W1b - W1c); k-frags consumed transiently
    f4 acc0[3];
    #pragma unroll
    for (int nt = 0; nt < 3; ++nt) {
        bf8 kb0 = wf[(nt * 6 + 4) * 64 + l];
        bf8 kb1 = wf[(nt * 6 + 5) * 64 + l];
        f4 z; z[0]=0.f; z[1]=0.f; z[2]=0.f; z[3]=0.f;
        z = __builtin_amdgcn_mfma_f32_16x16x32_bf16(ak[0], kb0, z, 0, 0, 0);
        z = __builtin_amdgcn_mfma_f32_16x16x32_bf16(ak[1], kb1, z, 0, 0, 0);
        acc0[nt] = z;
    }

    // per-u (output column) constants
    float b1v[3], dmv[3], drs[3], dav[3], w2v[3];
    #pragma unroll
    for (int nt = 0; nt < 3; ++nt) {
        int u = nt * 16 + ul;
        bool v = (u < NU);
        int uc = v ? u : (NU - 1);
        b1v[nt] = P.b1[uc];
        dmv[nt] = P.dm[uc];
        drs[nt] = rsqrtf(P.dv[uc] + 1e-6f);
        dav[nt] = P.da[uc];
        w2v[nt] = v ? P.W2[uc] : 0.f;
    }
    const float b2s = P.b2[0];

    for (int tt = w; tt < 13; tt += 4) {
        const int t0 = tt * 16;
        const int tA = t0 + (l & 15);           // A-frag row

        bf8 aq[2], ap[2];
        if (tA < NT) {
            const float* ubr = P.ub + ((size_t)b * NT + tA) * NE;
            #pragma unroll
            for (int ks = 0; ks < 2; ++ks) {
                int e0 = ks * 32 + 8 * (l >> 4);
                f4 u0 = *(const f4*)(ubr + e0);
                f4 u1 = *(const f4*)(ubr + e0 + 4);
                #pragma unroll
                for (int i = 0; i < 4; ++i) {
                    float q0 = u0[i], q1 = u1[i];
                    aq[ks][i]     = f2bf(q0);
                    aq[ks][4 + i] = f2bf(q1);
                    ap[ks][i]     = f2bf(q0 * bf2f(ak[ks][i]));
                    ap[ks][4 + i] = f2bf(q1 * bf2f(ak[ks][4 + i]));
                }
            }
        } else {
            #pragma unroll
            for (int ks = 0; ks < 2; ++ks)
                #pragma unroll
                for (int i = 0; i < 8; ++i) { aq[ks][i] = 0; ap[ks][i] = 0; }
        }

        f4 acc[3];
        #pragma unroll
        for (int nt = 0; nt < 3; ++nt) acc[nt] = acc0[nt];
        #pragma unroll
        for (int nt = 0; nt < 3; ++nt) {
            acc[nt] = __builtin_amdgcn_mfma_f32_16x16x32_bf16(aq[0], bfr[nt][0], acc[nt], 0, 0, 0);
            acc[nt] = __builtin_amdgcn_mfma_f32_16x16x32_bf16(aq[1], bfr[nt][1], acc[nt], 0, 0, 0);
            acc[nt] = __builtin_amdgcn_mfma_f32_16x16x32_bf16(ap[0], bfr[nt][2], acc[nt], 0, 0, 0);
            acc[nt] = __builtin_amdgcn_mfma_f32_16x16x32_bf16(ap[1], bfr[nt][3], acc[nt], 0, 0, 0);
        }

        // epilogue: D row = t0 + 4*(l>>4) + i, col u = nt*16 + (l&15)
        const int tD = t0 + 4 * (l >> 4);
        #pragma unroll
        for (int i = 0; i < 4; ++i) {
            int t = tD + i;
            bool tv = (t < NT);
            float val = 0.f;
            #pragma unroll
            for (int nt = 0; nt < 3; ++nt) {
                float x = acc[nt][i] + b1v[nt];
                float z = (x - dmv[nt]) * drs[nt];
                float p = 1.f / (1.f + __expf(-z));
                val += x * (dav[nt] + p * (1.f - dav[nt])) * w2v[nt];
            }
            val += __shfl_xor(val, 1);
            val += __shfl_xor(val, 2);
            val += __shfl_xor(val, 4);
            val += __shfl_xor(val, 8);
            if (ul == 0 && tv) w_s[t] = val + b2s;
        }
    }
    __syncthreads();

    // interest[e] = sum_t w[t]*ub[b,t,e]; BN1; write bf16 Hh row (64 wide)
    {
        const int e = tid & 63, g = tid >> 6;
        const float* ubb = P.ub + (size_t)b * NT * NE;
        float s = 0.f;
        #pragma unroll 5
        for (int t = g * 50; t < g * 50 + 50; ++t)
            s = fmaf(w_s[t], ubb[t * NE + e], s);
        red_s[tid] = s;
    }
    __syncthreads();
    if (tid < 64) {
        float tot = red_s[tid] + red_s[64 + tid] + red_s[128 + tid] + red_s[192 + tid];
        float hn = (tot - P.bn1_m[tid]) * rsqrtf(P.bn1_v[tid] + 1e-6f) * P.bn1_g[tid] + P.bn1_b[tid];
        P.Hh[((size_t)b * NTQ + tq) * 64 + tid] = f2bf(hn);
    }
}

// ---------------------------------------------------------------------------
// Kernel 2: batched trunk MLP. 100 blocks x 16 rows; 4 waves, wave w owns
// an N-quarter. Staging computes bn1(profile||context) cols on the fly.
// ---------------------------------------------------------------------------
struct TParams {
    const short *Hh, *wm1f, *wm2f, *wm3f;
    const float *up, *cx;
    const float *bn1_g, *bn1_b, *bn1_m, *bn1_v;
    const float *bm1, *bm2, *bm3;
    const float *bn2_g, *bn2_b, *bn2_m, *bn2_v;
    const float *bn3_g, *bn3_b, *bn3_m, *bn3_v;
    float* out;
};

#define LSTR 264   // bf16 row stride: 528B -> <=2-way bank aliasing (free)

__global__ __launch_bounds__(256) void trunk(TParams P) {
    __shared__ short Ha[16 * LSTR];
    __shared__ short Hb[16 * LSTR];

    const int tid = threadIdx.x;
    const int l = tid & 63, w = tid >> 6;
    const int row0 = blockIdx.x * 16;

    // stage cols 0..63 from Hh (attn output, already bn1'd)
    {
        const bf8* src = (const bf8*)(P.Hh + (size_t)row0 * 64);
        for (int ch = tid; ch < 16 * 8; ch += 256) {
            int r = ch >> 3, c8 = ch & 7;
            *(bf8*)&Ha[r * LSTR + c8 * 8] = src[r * 8 + c8];
        }
    }
    // stage cols 64..255 = bn1(profile || context), computed on the fly
    for (int ch = tid; ch < 16 * 192; ch += 256) {
        int r = ch / 192, c = ch % 192;
        int col = 64 + c;
        int b = (row0 + r) / NTQ;
        float val = (c < NP) ? P.up[b * NP + c] : P.cx[b * NC + (c - NP)];
        float hn = (val - P.bn1_m[col]) * rsqrtf(P.bn1_v[col] + 1e-6f)
                   * P.bn1_g[col] + P.bn1_b[col];
        Ha[r * LSTR + col] = f2bf(hn);
    }
    __syncthreads();

    const int ar = l & 15;            // A-frag row
    const int rl = 4 * (l >> 4);      // D row base
    const int nl = l & 15;            // D col within n-tile

    // ---- layer 1: K=256, N=256 : Ha -> Hb, relu then BN2 ----
    {
        bf8 a[8];
        #pragma unroll
        for (int ks = 0; ks < 8; ++ks)
            a[ks] = *(const bf8*)&Ha[ar * LSTR + ks * 32 + 8 * (l >> 4)];
        const bf8* wf = (const bf8*)P.wm1f;
        #pragma unroll
        for (int nt0 = 0; nt0 < 4; ++nt0) {
            int nt = w * 4 + nt0;
            f4 acc; acc[0]=0.f; acc[1]=0.f; acc[2]=0.f; acc[3]=0.f;
            #pragma unroll
            for (int ks = 0; ks < 8; ++ks)
                acc = __builtin_amdgcn_mfma_f32_16x16x32_bf16(a[ks], wf[(nt * 8 + ks) * 64 + l], acc, 0, 0, 0);
            int n = nt * 16 + nl;
            float g1 = P.bn2_g[n] * rsqrtf(P.bn2_v[n] + 1e-6f);
            float c1 = P.bn2_b[n] - P.bn2_m[n] * g1;
            float bias = P.bm1[n];
            #pragma unroll
            for (int i = 0; i < 4; ++i) {
                float v = fmaxf(acc[i] + bias, 0.f);
                Hb[(rl + i) * LSTR + n] = f2bf(v * g1 + c1);
            }
        }
    }
    __syncthreads();

    // ---- layer 2: K=256, N=128 : Hb -> Ha[:,0:128], relu then BN3 ----
    {
        bf8 a[8];
        #pragma unroll
        for (int ks = 0; ks < 8; ++ks)
            a[ks] = *(const bf8*)&Hb[ar * LSTR + ks * 32 + 8 * (l >> 4)];
        const bf8* wf = (const bf8*)P.wm2f;
        #pragma unroll
        for (int nt0 = 0; nt0 < 2; ++nt0) {
            int nt = w * 2 + nt0;
            f4 acc; acc[0]=0.f; acc[1]=0.f; acc[2]=0.f; acc[3]=0.f;
            #pragma unroll
            for (int ks = 0; ks < 8; ++ks)
                acc = __builtin_amdgcn_mfma_f32_16x16x32_bf16(a[ks], wf[(nt * 8 + ks) * 64 + l], acc, 0, 0, 0);
            int n = nt * 16 + nl;
            float g1 = P.bn3_g[n] * rsqrtf(P.bn3_v[n] + 1e-6f);
            float c1 = P.bn3_b[n] - P.bn3_m[n] * g1;
            float bias = P.bm2[n];
            #pragma unroll
            for (int i = 0; i < 4; ++i) {
                float v = fmaxf(acc[i] + bias, 0.f);
                Ha[(rl + i) * LSTR + n] = f2bf(v * g1 + c1);
            }
        }
    }
    __syncthreads();

    // ---- layer 3: K=128, N=64 : Ha[:,0:128] -> out, relu ----
    {
        bf8 a[4];
        #pragma unroll
        for (int ks = 0; ks < 4; ++ks)
            a[ks] = *(const bf8*)&Ha[ar * LSTR + ks * 32 + 8 * (l >> 4)];
        const bf8* wf = (const bf8*)P.wm3f;
        {
            int nt = w;
            f4 acc; acc[0]=0.f; acc[1]=0.f; acc[2]=0.f; acc[3]=0.f;
            #pragma unroll
            for (int ks = 0; ks < 4; ++ks)
                acc = __builtin_amdgcn_mfma_f32_16x16x32_bf16(a[ks], wf[(nt * 4 + ks) * 64 + l], acc, 0, 0, 0);
            int n = nt * 16 + nl;
            float bias = P.bm3[n];
            #pragma unroll
            for (int i = 0; i < 4; ++i)
                P.out[(size_t)(row0 + rl + i) * 64 + n] = fmaxf(acc[i] + bias, 0.f);
        }
    }
}

// ---------------------------------------------------------------------------
extern "C" void kernel_launch(void* const* d_in, const int* in_sizes, int n_in,
                              void* d_out, int out_size, void* d_ws, size_t ws_size,
                              hipStream_t stream) {
    (void)in_sizes; (void)n_in; (void)out_size; (void)ws_size;

    const float* ub         = (const float*)d_in[0];
    const float* it         = (const float*)d_in[1];
    const float* up         = (const float*)d_in[2];
    const float* cx         = (const float*)d_in[3];
    const float* W1         = (const float*)d_in[4];
    const float* b1         = (const float*)d_in[5];
    const float* dice_alpha = (const float*)d_in[6];
    const float* dice_mean  = (const float*)d_in[7];
    const float* dice_var   = (const float*)d_in[8];
    const float* W2         = (const float*)d_in[9];
    const float* b2         = (const float*)d_in[10];
    const float* bn1_g      = (const float*)d_in[11];
    const float* bn1_b      = (const float*)d_in[12];
    const float* bn1_m      = (const float*)d_in[13];
    const float* bn1_v      = (const float*)d_in[14];
    const float* Wm1        = (const float*)d_in[15];
    const float* bm1        = (const float*)d_in[16];
    const float* bn2_g      = (const float*)d_in[17];
    const float* bn2_b      = (const float*)d_in[18];
    const float* bn2_m      = (const float*)d_in[19];
    const float* bn2_v      = (const float*)d_in[20];
    const float* Wm2        = (const float*)d_in[21];
    const float* bm2        = (const float*)d_in[22];
    const float* bn3_g      = (const float*)d_in[23];
    const float* bn3_b      = (const float*)d_in[24];
    const float* bn3_m      = (const float*)d_in[25];
    const float* bn3_v      = (const float*)d_in[26];
    const float* Wm3        = (const float*)d_in[27];
    const float* bm3        = (const float*)d_in[28];

    short* wsb  = (short*)d_ws;
    short* wm1f = wsb + WM1F_OFF;
    short* wm2f = wsb + WM2F_OFF;
    short* wm3f = wsb + WM3F_OFF;
    short* w1f  = wsb + W1F_OFF;
    short* Hh   = wsb + HH_OFF;

    prep_w1<<<36, 256, 0, stream>>>(W1, w1f);

    AParams A;
    A.ub = ub; A.it = it; A.b1 = b1;
    A.W2 = W2; A.b2 = b2; A.da = dice_alpha; A.dm = dice_mean; A.dv = dice_var;
    A.bn1_g = bn1_g; A.bn1_b = bn1_b; A.bn1_m = bn1_m; A.bn1_v = bn1_v;
    A.Wm1 = Wm1; A.Wm2 = Wm2; A.Wm3 = Wm3;
    A.w1f = w1f; A.wm1f = wm1f; A.wm2f = wm2f; A.wm3f = wm3f;
    A.Hh = Hh;
    attn<<<ATTN_BLOCKS + PACK_BLOCKS, 256, 0, stream>>>(A);

    TParams T;
    T.Hh = Hh; T.wm1f = wm1f; T.wm2f = wm2f; T.wm3f = wm3f;
    T.up = up; T.cx = cx;
    T.bn1_g = bn1_g; T.bn1_b = bn1_b; T.bn1_m = bn1_m; T.bn1_v = bn1_v;
    T.bm1 = bm1; T.bm2 = bm2; T.bm3 = bm3;
    T.bn2_g = bn2_g; T.bn2_b = bn2_b; T.bn2_m = bn2_m; T.bn2_v = bn2_v;
    T.bn3_g = bn3_g; T.bn3_b = bn3_b; T.bn3_m = bn3_m; T.bn3_v = bn3_v;
    T.out = (float*)d_out;
    trunk<<<NROW / 16, 256, 0, stream>>>(T);
}